// Round 5
// baseline (2800.933 us; speedup 1.0000x reference)
//
#include <hip/hip_runtime.h>
#include <hip/hip_bf16.h>
#include <stdint.h>

#define B_ 4
#define H_ 160
#define W_ 160

typedef __hip_bfloat16 bf16;

// ---------------- static workspace (module .bss, no d_ws dependency) ----------------
__device__ float g_A1[6553600];     // (4,64,160,160)
__device__ float g_A2[6553600];
__device__ float g_F1[6553600];
__device__ float g_CO[22118400];    // (4,216,160,160)
__device__ float g_WT[470016];      // transposed conv weights, f32
__device__ bf16  g_WD[82944];       // 2 x [576][72] transposed dcn weights (bf16)

// buffer ids: 0 = use passed pointer, 1=A1, 2=A2, 3=F1, 4=CO
__device__ __forceinline__ const float* rsrc(const float* p, int id) {
  if (id == 1) return g_A1;
  if (id == 2) return g_A2;
  if (id == 3) return g_F1;
  if (id == 4) return g_CO;
  return p;
}
__device__ __forceinline__ float* rdst(float* p, int id) {
  if (id == 1) return g_A1;
  if (id == 2) return g_A2;
  if (id == 3) return g_F1;
  if (id == 4) return g_CO;
  return p;
}

// ---------------- weight prep ----------------
// conv weights: src f32 [OC][K] -> g_WT[off + k*OC + oc]   (K = CIN*9)
__global__ void prep_wconv(const float* __restrict__ src, int off, int OC, int K) {
  int i = blockIdx.x * 256 + threadIdx.x;
  if (i < OC * K) {
    int oc = i / K, k = i - oc * K;
    g_WT[off + k * OC + oc] = src[i];
  }
}
// dcn weights: src f32 [64][576] -> g_WD[off + k*72 + oc] bf16 (cols 64..71 zeroed)
__global__ void prep_wdcn(const float* __restrict__ src, int off) {
  int i = blockIdx.x * 256 + threadIdx.x;
  if (i < 576 * 72) {
    int k = i / 72, oc = i - k * 72;
    g_WD[off + i] = __float2bfloat16((oc < 64) ? src[oc * 576 + k] : 0.f);
  }
}

// ---------------- direct conv3x3, pad=1 ----------------
// grid: (100 tiles, ceil(OC/16), B). block 256 = 16x16 pixels. 16 oc/thread.
#define FMA16(xv, base) { \
  float4 a0 = w4[(base)];   float4 a1 = w4[(base)+1]; \
  float4 a2 = w4[(base)+2]; float4 a3 = w4[(base)+3]; \
  acc[0]+=(xv)*a0.x; acc[1]+=(xv)*a0.y; acc[2]+=(xv)*a0.z; acc[3]+=(xv)*a0.w; \
  acc[4]+=(xv)*a1.x; acc[5]+=(xv)*a1.y; acc[6]+=(xv)*a1.z; acc[7]+=(xv)*a1.w; \
  acc[8]+=(xv)*a2.x; acc[9]+=(xv)*a2.y; acc[10]+=(xv)*a2.z; acc[11]+=(xv)*a2.w; \
  acc[12]+=(xv)*a3.x; acc[13]+=(xv)*a3.y; acc[14]+=(xv)*a3.z; acc[15]+=(xv)*a3.w; }

__global__ __launch_bounds__(256)
void conv3x3_k(const float* in1p, int in1_id, int c1,
               const float* in2p, int in2_id, int c2,
               int wt_off, const float* __restrict__ bias,
               float* outp, int out_id, int OC, int act)
{
  const float* in1 = rsrc(in1p, in1_id);
  const float* in2 = rsrc(in2p, in2_id);
  float* out = rdst(outp, out_id);
  const float* WT = g_WT + wt_off;   // [CIN*9][OC]
  __shared__ __align__(16) float XS[8][18][18];
  __shared__ __align__(16) float WS[8][9][16];
  int tid = threadIdx.x;
  int tx = tid & 15, ty = tid >> 4;
  int bx = blockIdx.x;
  int tx0 = (bx % 10) * 16, ty0 = (bx / 10) * 16;
  int ocb = blockIdx.y;
  int b = blockIdx.z;
  int CIN = c1 + c2;
  float acc[16];
#pragma unroll
  for (int i = 0; i < 16; ++i) acc[i] = 0.f;

  for (int cb = 0; cb < CIN; cb += 8) {
    __syncthreads();
    // stage input tile 8 x 18 x 18 (zero-padded at image border)
    for (int i = tid; i < 8 * 324; i += 256) {
      int ci8 = i / 324; int r = i - ci8 * 324;
      int yy = r / 18, xx = r - yy * 18;
      int gy = ty0 + yy - 1, gx = tx0 + xx - 1;
      int gc = cb + ci8;
      float v = 0.f;
      if (gy >= 0 && gy < H_ && gx >= 0 && gx < W_) {
        if (gc < c1) v = in1[((b * c1 + gc) * H_ + gy) * W_ + gx];
        else         v = in2[((b * c2 + (gc - c1)) * H_ + gy) * W_ + gx];
      }
      XS[ci8][yy][xx] = v;
    }
    // stage weights [ci8][tap][16 oc]
    for (int i = tid; i < 8 * 9 * 16; i += 256) {
      int j = i & 15; int rt = i >> 4;      // rt = ci8*9+tap
      int goc = ocb * 16 + j;
      float wv = 0.f;
      if (goc < OC) wv = WT[(cb * 9 + rt) * OC + goc];
      ((float*)WS)[i] = wv;
    }
    __syncthreads();
    for (int ci8 = 0; ci8 < 8; ++ci8) {
      const float4* w4 = (const float4*)(&WS[ci8][0][0]);
#pragma unroll
      for (int ky = 0; ky < 3; ++ky) {
        int row = ty + ky;
        float xv0 = XS[ci8][row][tx];
        float xv1 = XS[ci8][row][tx + 1];
        float xv2 = XS[ci8][row][tx + 2];
        FMA16(xv0, (ky * 3 + 0) * 4);
        FMA16(xv1, (ky * 3 + 1) * 4);
        FMA16(xv2, (ky * 3 + 2) * 4);
      }
    }
  }
  int px = tx0 + tx, py = ty0 + ty;
#pragma unroll
  for (int j = 0; j < 16; ++j) {
    int goc = ocb * 16 + j;
    if (goc < OC) {
      float v = acc[j] + bias[goc];
      if (act) v = v > 0.f ? v : 0.1f * v;
      out[((b * OC + goc) * H_ + py) * W_ + px] = v;
    }
  }
}

// ---------------- fused modulated deformable conv ----------------
// grid: (H*(W/32), B). block 256. 32 pixels x 64 oc per block.
#define ACC8(vv, u) { \
  acc[0] += (vv) * __uint_as_float((u).x << 16); \
  acc[1] += (vv) * __uint_as_float((u).x & 0xffff0000u); \
  acc[2] += (vv) * __uint_as_float((u).y << 16); \
  acc[3] += (vv) * __uint_as_float((u).y & 0xffff0000u); \
  acc[4] += (vv) * __uint_as_float((u).z << 16); \
  acc[5] += (vv) * __uint_as_float((u).z & 0xffff0000u); \
  acc[6] += (vv) * __uint_as_float((u).w << 16); \
  acc[7] += (vv) * __uint_as_float((u).w & 0xffff0000u); }

__global__ __launch_bounds__(256)
void dcn_k(const float* xp, int x_id,
           int wd_off, const float* __restrict__ bias,
           float* outp, int out_id)
{
  const float* x = rsrc(xp, x_id);
  const float* co = g_CO;                       // (B,216,H,W)
  const bf16* WD = g_WD + wd_off;               // [576][72]
  float* out = rdst(outp, out_id);
  __shared__ __align__(16) bf16 vS[32 * 578];   // [pixel][K] pad-stride 578
  __shared__ __align__(16) bf16 wS[96 * 72];    // K-chunk of weights
  int tid = threadIdx.x;
  int b = blockIdx.y;
  int h = blockIdx.x / 5;
  int w0 = (blockIdx.x % 5) * 32;

  // ---- phase A: sample 32px x 8g x 9k, 8 ch each -> vS ----
  const float* cob = co + ((size_t)b * 216 * H_ * W_) + h * W_ + w0;
#pragma unroll
  for (int t = 0; t < 9; ++t) {
    int idx = t * 256 + tid;      // 0..2303 = 72 gk * 32 px
    int gk = idx >> 5;
    int p = idx & 31;
    int g = gk / 9, kk = gk - g * 9;
    float offy = cob[(gk * 2) * (H_ * W_) + p];
    float offx = cob[(gk * 2 + 1) * (H_ * W_) + p];
    float mval = cob[(144 + gk) * (H_ * W_) + p];
    float mask = 1.f / (1.f + __expf(-mval));
    float pyf = offy + (float)(kk / 3 - 1 + h);
    float pxf = offx + (float)(kk % 3 - 1 + w0 + p);
    float y0f = floorf(pyf), x0f = floorf(pxf);
    float ly = pyf - y0f, lx = pxf - x0f;
    int iy0 = (int)y0f, ix0 = (int)x0f;
    int iy1 = iy0 + 1, ix1 = ix0 + 1;
    float w00 = (1.f - ly) * (1.f - lx) * mask;
    float w01 = (1.f - ly) * lx * mask;
    float w10 = ly * (1.f - lx) * mask;
    float w11 = ly * lx * mask;
    if (iy0 < 0 || iy0 >= H_) { w00 = 0.f; w01 = 0.f; }
    if (iy1 < 0 || iy1 >= H_) { w10 = 0.f; w11 = 0.f; }
    if (ix0 < 0 || ix0 >= W_) { w00 = 0.f; w10 = 0.f; }
    if (ix1 < 0 || ix1 >= W_) { w01 = 0.f; w11 = 0.f; }
    int cy0 = min(max(iy0, 0), H_ - 1), cy1 = min(max(iy1, 0), H_ - 1);
    int cx0 = min(max(ix0, 0), W_ - 1), cx1 = min(max(ix1, 0), W_ - 1);
    int base = ((b * 64 + g * 8) * H_) * W_;
    int a00 = base + cy0 * W_ + cx0, a01 = base + cy0 * W_ + cx1;
    int a10 = base + cy1 * W_ + cx0, a11 = base + cy1 * W_ + cx1;
    bf16* vrow = vS + p * 578 + g * 72 + kk;
#pragma unroll
    for (int c = 0; c < 8; ++c) {
      int o = c * (H_ * W_);
      float v = w00 * x[a00 + o] + w01 * x[a01 + o]
              + w10 * x[a10 + o] + w11 * x[a11 + o];
      vrow[c * 9] = __float2bfloat16(v);
    }
  }

  // ---- phase B: out[p][oc] = sum_K v[p][K] * w[K][oc] ----
  int p = tid >> 3, og = tid & 7;   // 32 px x 8 oc-groups, 8 oc each
  float acc[8];
#pragma unroll
  for (int j = 0; j < 8; ++j) acc[j] = 0.f;
  for (int kc = 0; kc < 576; kc += 96) {
    __syncthreads();
    const uint4* gsrc = (const uint4*)(WD + kc * 72);
    uint4* wdst = (uint4*)wS;
    for (int i = tid; i < 96 * 72 * 2 / 16; i += 256) wdst[i] = gsrc[i];
    __syncthreads();
#pragma unroll 4
    for (int k2 = 0; k2 < 96; k2 += 2) {
      uint32_t vv = *(const uint32_t*)(vS + p * 578 + kc + k2);
      float v0 = __uint_as_float(vv << 16);
      float v1 = __uint_as_float(vv & 0xffff0000u);
      uint4 u0 = *(const uint4*)(wS + k2 * 72 + og * 8);
      uint4 u1 = *(const uint4*)(wS + (k2 + 1) * 72 + og * 8);
      ACC8(v0, u0);
      ACC8(v1, u1);
    }
  }
  __syncthreads();
  // restage outputs through LDS for coalesced stores
  float* outS = (float*)vS;          // 64*33 floats fits easily
#pragma unroll
  for (int j = 0; j < 8; ++j) {
    int oc = og * 8 + j;
    float v = acc[j] + bias[oc];
    v = v > 0.f ? v : 0.1f * v;
    outS[oc * 33 + p] = v;
  }
  __syncthreads();
  for (int i = tid; i < 2048; i += 256) {
    int oc = i >> 5, p2 = i & 31;
    float v = outS[oc * 33 + p2];
    int oi = ((b * 64 + oc) * H_ + h) * W_ + w0 + p2;
    out[oi] = v;
  }
}

extern "C" void kernel_launch(void* const* d_in, const int* in_sizes, int n_in,
                              void* d_out, int out_size, void* d_ws, size_t ws_size,
                              hipStream_t stream) {
  (void)in_sizes; (void)n_in; (void)out_size; (void)d_ws; (void)ws_size;
  const float* nbr    = (const float*)d_in[0];
  const float* ref    = (const float*)d_in[1];
  const float* w_off1 = (const float*)d_in[2];
  const float* b_off1 = (const float*)d_in[3];
  const float* w_off2 = (const float*)d_in[4];
  const float* b_off2 = (const float*)d_in[5];
  const float* w_co   = (const float*)d_in[6];
  const float* b_co   = (const float*)d_in[7];
  const float* w_dcn  = (const float*)d_in[8];
  const float* b_dcn  = (const float*)d_in[9];
  const float* w_coff1= (const float*)d_in[10];
  const float* b_coff1= (const float*)d_in[11];
  const float* w_coff2= (const float*)d_in[12];
  const float* b_coff2= (const float*)d_in[13];
  const float* w_cco  = (const float*)d_in[14];
  const float* b_cco  = (const float*)d_in[15];
  const float* w_cdcn = (const float*)d_in[16];
  const float* b_cdcn = (const float*)d_in[17];

  // g_WT offsets (floats): WT1=0, WT2=73728, WTco=110592, WTc1=235008,
  //                        WTc2=308736, WTcco=345600   (total 470016)
  // g_WD offsets (bf16):   WD1=0, WD2=41472
  prep_wconv<<<288, 256, 0, stream>>>(w_off1, 0, 64, 1152);
  prep_wconv<<<144, 256, 0, stream>>>(w_off2, 73728, 64, 576);
  prep_wconv<<<486, 256, 0, stream>>>(w_co, 110592, 216, 576);
  prep_wconv<<<288, 256, 0, stream>>>(w_coff1, 235008, 64, 1152);
  prep_wconv<<<144, 256, 0, stream>>>(w_coff2, 308736, 64, 576);
  prep_wconv<<<486, 256, 0, stream>>>(w_cco, 345600, 216, 576);
  prep_wdcn<<<162, 256, 0, stream>>>(w_dcn, 0);
  prep_wdcn<<<162, 256, 0, stream>>>(w_cdcn, 41472);

  dim3 cg(100, 4, 4), cgco(100, 14, 4), blk(256);
  dim3 dg(800, 4);
  float* out = (float*)d_out;
  // A1 = lrelu(conv(cat(nbr,ref))); A2 = lrelu(conv(A1))
  conv3x3_k<<<cg, blk, 0, stream>>>(nbr, 0, 64, ref, 0, 64, 0, b_off1, nullptr, 1, 64, 1);
  conv3x3_k<<<cg, blk, 0, stream>>>(nullptr, 1, 64, nullptr, 0, 0, 73728, b_off2, nullptr, 2, 64, 1);
  // CO = conv(A2); F1 = lrelu(dcn(nbr, CO))
  conv3x3_k<<<cgco, blk, 0, stream>>>(nullptr, 2, 64, nullptr, 0, 0, 110592, b_co, nullptr, 4, 216, 0);
  dcn_k<<<dg, blk, 0, stream>>>(nbr, 0, 0, b_dcn, nullptr, 3);
  // cascade
  conv3x3_k<<<cg, blk, 0, stream>>>(nullptr, 3, 64, ref, 0, 64, 235008, b_coff1, nullptr, 1, 64, 1);
  conv3x3_k<<<cg, blk, 0, stream>>>(nullptr, 1, 64, nullptr, 0, 0, 308736, b_coff2, nullptr, 2, 64, 1);
  conv3x3_k<<<cgco, blk, 0, stream>>>(nullptr, 2, 64, nullptr, 0, 0, 345600, b_cco, nullptr, 4, 216, 0);
  dcn_k<<<dg, blk, 0, stream>>>(nullptr, 3, 41472, b_cdcn, out, 0);
}

// Round 6
// 1307.223 us; speedup vs baseline: 2.1427x; 2.1427x over previous
//
#include <hip/hip_runtime.h>
#include <hip/hip_bf16.h>
#include <stdint.h>

#define B_ 4
#define H_ 160
#define W_ 160

typedef __hip_bfloat16 bf16;
typedef __attribute__((ext_vector_type(8))) short bf16x8;   // 8 bf16 = 4 VGPRs
typedef __attribute__((ext_vector_type(4))) float f32x4;

// ---------------- static workspace (module .bss) ----------------
__device__ float g_A1[6553600];     // (4,64,160,160)
__device__ float g_A2[6553600];
__device__ float g_F1[6553600];
__device__ float g_CO[22118400];    // (4,216,160,160)
__device__ __align__(16) bf16 g_WB[516096];  // conv weights, B-fragment order
__device__ __align__(16) bf16 g_WD[82944];   // 2 x [576][72] dcn weights

// buffer ids: 0 = use passed pointer, 1=A1, 2=A2, 3=F1, 4=CO
__device__ __forceinline__ const float* rsrc(const float* p, int id) {
  if (id == 1) return g_A1;
  if (id == 2) return g_A2;
  if (id == 3) return g_F1;
  if (id == 4) return g_CO;
  return p;
}
__device__ __forceinline__ float* rdst(float* p, int id) {
  if (id == 1) return g_A1;
  if (id == 2) return g_A2;
  if (id == 3) return g_F1;
  if (id == 4) return g_CO;
  return p;
}

// ---------------- weight prep: B-fragment order ----------------
// layout: [nb][cc][tap][ntile][lane][8j], frag element (lane,j):
//   oc = nb*64 + ntile*16 + (lane&15), ci = cc*32 + (lane>>4)*8 + j
__global__ void prep_wfrag(const float* __restrict__ src, int off,
                           int OC, int CIN, int NB) {
  int i = blockIdx.x * 256 + threadIdx.x;
  int CC = CIN >> 5;
  int total = NB * CC * 18432;
  if (i >= total) return;
  int j = i & 7;
  int t = i >> 3;
  int lane = t & 63; t >>= 6;
  int nt = t & 3; t >>= 2;
  int tap = t % 9; t /= 9;
  int cc = t % CC; int nb = t / CC;
  int oc = nb * 64 + nt * 16 + (lane & 15);
  int ci = cc * 32 + (lane >> 4) * 8 + j;
  float v = (oc < OC) ? src[(oc * CIN + ci) * 9 + tap] : 0.f;
  g_WB[off + i] = __float2bfloat16(v);
}

// dcn weights: src f32 [64][576] -> g_WD[off + k*72 + oc] bf16 (cols 64..71 zero)
__global__ void prep_wdcn(const float* __restrict__ src, int off) {
  int i = blockIdx.x * 256 + threadIdx.x;
  if (i < 576 * 72) {
    int k = i / 72, oc = i - k * 72;
    g_WD[off + i] = __float2bfloat16((oc < 64) ? src[oc * 576 + k] : 0.f);
  }
}

// ---------------- MFMA conv3x3, pad=1 ----------------
// grid: (400 = 80 row-pairs x 5 col-tiles, NB, B). block 256 = 4 waves.
// block tile: 64 px (2 rows x 32 cols) x 64 oc. wave: 16 px x 64 oc.
__global__ __launch_bounds__(256)
void conv_mfma(const float* in1p, int id1, int c1,
               const float* in2p, int id2, int c2,
               int woff, int CC, const float* __restrict__ bias,
               float* outp, int out_id, int OC, int act)
{
  const float* in1 = rsrc(in1p, id1);
  const float* in2 = rsrc(in2p, id2);
  float* out = rdst(outp, out_id);

  __shared__ __align__(16) bf16 XS[5440];   // [4 rows][34 cols][ci pad 40]
  __shared__ float OS[4224];                // [64 oc][66]

  int tid = threadIdx.x;
  int bx = blockIdx.x;
  int r0 = 2 * (bx / 5), c0 = 32 * (bx % 5);
  int nb = blockIdx.y;
  int b = blockIdx.z;
  const bf16* wblk = g_WB + woff + nb * CC * 18432;

  int w = tid >> 6;          // wave id
  int L = tid & 63;
  int lm = L & 15;           // A row / B col within tile
  int k0 = (L >> 4) * 8;     // k-offset within 32-chunk
  int mrow = w >> 1;         // output row within 2-row tile
  int mcolb = (w & 1) * 16;  // output col base within 32-col tile

  f32x4 acc[4];
#pragma unroll
  for (int nt = 0; nt < 4; ++nt) acc[nt] = (f32x4)0.f;

  for (int cc = 0; cc < CC; ++cc) {
    int cb = cc * 32;
    __syncthreads();
    // ---- stage X tile: rows r0-1..r0+2, cols c0-1..c0+32, 32 ci ----
    {
      int colm = 1 + (tid & 31);            // interior cols 1..32
      int sub = tid >> 5;                   // 0..7
#pragma unroll
      for (int t = 0; t < 16; ++t) {
        int idx = t * 8 + sub;              // 0..127
        int ci = idx & 31, row = idx >> 5;
        int gy = r0 - 1 + row;
        int gx = c0 + (tid & 31);           // in-range in x always
        int gc = cb + ci;
        float v = 0.f;
        if (gy >= 0 && gy < H_) {
          v = (gc < c1) ? in1[((b * c1 + gc) * H_ + gy) * W_ + gx]
                        : in2[((b * c2 + gc - c1) * H_ + gy) * W_ + gx];
        }
        XS[(row * 34 + colm) * 40 + ci] = __float2bfloat16(v);
      }
      // halo cols 0 and 33 (one element per thread)
      int hc = (tid & 1) * 33;
      int idx2 = tid >> 1;                  // 0..127
      int ci = idx2 & 31, row = idx2 >> 5;
      int gy = r0 - 1 + row;
      int gx = c0 - 1 + hc;
      int gc = cb + ci;
      float v = 0.f;
      if (gy >= 0 && gy < H_ && gx >= 0 && gx < W_) {
        v = (gc < c1) ? in1[((b * c1 + gc) * H_ + gy) * W_ + gx]
                      : in2[((b * c2 + gc - c1) * H_ + gy) * W_ + gx];
      }
      XS[(row * 34 + hc) * 40 + ci] = __float2bfloat16(v);
    }
    __syncthreads();
    // ---- 9 taps x 4 n-tiles of MFMA ----
#pragma unroll 3
    for (int tap = 0; tap < 9; ++tap) {
      int dyp = tap / 3, dxp = tap - dyp * 3;
      bf16x8 a = *(const bf16x8*)&XS[((mrow + dyp) * 34 + mcolb + lm + dxp) * 40 + k0];
      const bf16* wb = wblk + (cc * 9 + tap) * 2048 + L * 8;
#pragma unroll
      for (int nt = 0; nt < 4; ++nt) {
        bf16x8 bf = *(const bf16x8*)(wb + nt * 512);
        acc[nt] = __builtin_amdgcn_mfma_f32_16x16x32_bf16(a, bf, acc[nt], 0, 0, 0);
      }
    }
  }

  // ---- epilogue: restage through LDS, coalesced store ----
  __syncthreads();
#pragma unroll
  for (int nt = 0; nt < 4; ++nt)
#pragma unroll
    for (int r = 0; r < 4; ++r) {
      int oc_l = nt * 16 + lm;
      int m = w * 16 + (L >> 4) * 4 + r;
      OS[oc_l * 66 + m] = acc[nt][r];
    }
  __syncthreads();
  for (int i = tid; i < 4096; i += 256) {
    int oc_l = i >> 6, m = i & 63;
    int oc = nb * 64 + oc_l;
    if (oc < OC) {
      float v = OS[oc_l * 66 + m] + bias[oc];
      if (act) v = v > 0.f ? v : 0.1f * v;
      int py = r0 + (m >> 5), px = c0 + (m & 31);
      out[((b * OC + oc) * H_ + py) * W_ + px] = v;
    }
  }
}

// ---------------- fused modulated deformable conv (unchanged) ----------------
#define ACC8(vv, u) { \
  acc[0] += (vv) * __uint_as_float((u).x << 16); \
  acc[1] += (vv) * __uint_as_float((u).x & 0xffff0000u); \
  acc[2] += (vv) * __uint_as_float((u).y << 16); \
  acc[3] += (vv) * __uint_as_float((u).y & 0xffff0000u); \
  acc[4] += (vv) * __uint_as_float((u).z << 16); \
  acc[5] += (vv) * __uint_as_float((u).z & 0xffff0000u); \
  acc[6] += (vv) * __uint_as_float((u).w << 16); \
  acc[7] += (vv) * __uint_as_float((u).w & 0xffff0000u); }

__global__ __launch_bounds__(256)
void dcn_k(const float* xp, int x_id,
           int wd_off, const float* __restrict__ bias,
           float* outp, int out_id)
{
  const float* x = rsrc(xp, x_id);
  const float* co = g_CO;                       // (B,216,H,W)
  const bf16* WD = g_WD + wd_off;               // [576][72]
  float* out = rdst(outp, out_id);
  __shared__ __align__(16) bf16 vS[32 * 578];   // [pixel][K] pad-stride 578
  __shared__ __align__(16) bf16 wS[96 * 72];    // K-chunk of weights
  int tid = threadIdx.x;
  int b = blockIdx.y;
  int h = blockIdx.x / 5;
  int w0 = (blockIdx.x % 5) * 32;

  const float* cob = co + ((size_t)b * 216 * H_ * W_) + h * W_ + w0;
#pragma unroll
  for (int t = 0; t < 9; ++t) {
    int idx = t * 256 + tid;      // 0..2303 = 72 gk * 32 px
    int gk = idx >> 5;
    int p = idx & 31;
    int g = gk / 9, kk = gk - g * 9;
    float offy = cob[(gk * 2) * (H_ * W_) + p];
    float offx = cob[(gk * 2 + 1) * (H_ * W_) + p];
    float mval = cob[(144 + gk) * (H_ * W_) + p];
    float mask = 1.f / (1.f + __expf(-mval));
    float pyf = offy + (float)(kk / 3 - 1 + h);
    float pxf = offx + (float)(kk % 3 - 1 + w0 + p);
    float y0f = floorf(pyf), x0f = floorf(pxf);
    float ly = pyf - y0f, lx = pxf - x0f;
    int iy0 = (int)y0f, ix0 = (int)x0f;
    int iy1 = iy0 + 1, ix1 = ix0 + 1;
    float w00 = (1.f - ly) * (1.f - lx) * mask;
    float w01 = (1.f - ly) * lx * mask;
    float w10 = ly * (1.f - lx) * mask;
    float w11 = ly * lx * mask;
    if (iy0 < 0 || iy0 >= H_) { w00 = 0.f; w01 = 0.f; }
    if (iy1 < 0 || iy1 >= H_) { w10 = 0.f; w11 = 0.f; }
    if (ix0 < 0 || ix0 >= W_) { w00 = 0.f; w10 = 0.f; }
    if (ix1 < 0 || ix1 >= W_) { w01 = 0.f; w11 = 0.f; }
    int cy0 = min(max(iy0, 0), H_ - 1), cy1 = min(max(iy1, 0), H_ - 1);
    int cx0 = min(max(ix0, 0), W_ - 1), cx1 = min(max(ix1, 0), W_ - 1);
    int base = ((b * 64 + g * 8) * H_) * W_;
    int a00 = base + cy0 * W_ + cx0, a01 = base + cy0 * W_ + cx1;
    int a10 = base + cy1 * W_ + cx0, a11 = base + cy1 * W_ + cx1;
    bf16* vrow = vS + p * 578 + g * 72 + kk;
#pragma unroll
    for (int c = 0; c < 8; ++c) {
      int o = c * (H_ * W_);
      float v = w00 * x[a00 + o] + w01 * x[a01 + o]
              + w10 * x[a10 + o] + w11 * x[a11 + o];
      vrow[c * 9] = __float2bfloat16(v);
    }
  }

  int p = tid >> 3, og = tid & 7;
  float acc[8];
#pragma unroll
  for (int j = 0; j < 8; ++j) acc[j] = 0.f;
  for (int kc = 0; kc < 576; kc += 96) {
    __syncthreads();
    const uint4* gsrc = (const uint4*)(WD + kc * 72);
    uint4* wdst = (uint4*)wS;
    for (int i = tid; i < 96 * 72 * 2 / 16; i += 256) wdst[i] = gsrc[i];
    __syncthreads();
#pragma unroll 4
    for (int k2 = 0; k2 < 96; k2 += 2) {
      uint32_t vv = *(const uint32_t*)(vS + p * 578 + kc + k2);
      float v0 = __uint_as_float(vv << 16);
      float v1 = __uint_as_float(vv & 0xffff0000u);
      uint4 u0 = *(const uint4*)(wS + k2 * 72 + og * 8);
      uint4 u1 = *(const uint4*)(wS + (k2 + 1) * 72 + og * 8);
      ACC8(v0, u0);
      ACC8(v1, u1);
    }
  }
  __syncthreads();
  float* outS = (float*)vS;
#pragma unroll
  for (int j = 0; j < 8; ++j) {
    int oc = og * 8 + j;
    float v = acc[j] + bias[oc];
    v = v > 0.f ? v : 0.1f * v;
    outS[oc * 33 + p] = v;
  }
  __syncthreads();
  for (int i = tid; i < 2048; i += 256) {
    int oc = i >> 5, p2 = i & 31;
    float v = outS[oc * 33 + p2];
    int oi = ((b * 64 + oc) * H_ + h) * W_ + w0 + p2;
    out[oi] = v;
  }
}

extern "C" void kernel_launch(void* const* d_in, const int* in_sizes, int n_in,
                              void* d_out, int out_size, void* d_ws, size_t ws_size,
                              hipStream_t stream) {
  (void)in_sizes; (void)n_in; (void)out_size; (void)d_ws; (void)ws_size;
  const float* nbr    = (const float*)d_in[0];
  const float* ref    = (const float*)d_in[1];
  const float* w_off1 = (const float*)d_in[2];
  const float* b_off1 = (const float*)d_in[3];
  const float* w_off2 = (const float*)d_in[4];
  const float* b_off2 = (const float*)d_in[5];
  const float* w_co   = (const float*)d_in[6];
  const float* b_co   = (const float*)d_in[7];
  const float* w_dcn  = (const float*)d_in[8];
  const float* b_dcn  = (const float*)d_in[9];
  const float* w_coff1= (const float*)d_in[10];
  const float* b_coff1= (const float*)d_in[11];
  const float* w_coff2= (const float*)d_in[12];
  const float* b_coff2= (const float*)d_in[13];
  const float* w_cco  = (const float*)d_in[14];
  const float* b_cco  = (const float*)d_in[15];
  const float* w_cdcn = (const float*)d_in[16];
  const float* b_cdcn = (const float*)d_in[17];

  // g_WB offsets (bf16): c1=0(73728) c2=73728(36864) co=110592(147456)
  //                      cc1=258048 cc2=331776 cco=368640  total 516096
  prep_wfrag<<<288, 256, 0, stream>>>(w_off1, 0, 64, 128, 1);
  prep_wfrag<<<144, 256, 0, stream>>>(w_off2, 73728, 64, 64, 1);
  prep_wfrag<<<576, 256, 0, stream>>>(w_co, 110592, 216, 64, 4);
  prep_wfrag<<<288, 256, 0, stream>>>(w_coff1, 258048, 64, 128, 1);
  prep_wfrag<<<144, 256, 0, stream>>>(w_coff2, 331776, 64, 64, 1);
  prep_wfrag<<<576, 256, 0, stream>>>(w_cco, 368640, 216, 64, 4);
  prep_wdcn<<<162, 256, 0, stream>>>(w_dcn, 0);
  prep_wdcn<<<162, 256, 0, stream>>>(w_cdcn, 41472);

  dim3 blk(256);
  float* out = (float*)d_out;
  // A1 = lrelu(conv(cat(nbr,ref))); A2 = lrelu(conv(A1))
  conv_mfma<<<dim3(400, 1, 4), blk, 0, stream>>>(nbr, 0, 64, ref, 0, 64, 0, 4, b_off1, nullptr, 1, 64, 1);
  conv_mfma<<<dim3(400, 1, 4), blk, 0, stream>>>(nullptr, 1, 64, nullptr, 0, 0, 73728, 2, b_off2, nullptr, 2, 64, 1);
  // CO = conv(A2); F1 = lrelu(dcn(nbr, CO))
  conv_mfma<<<dim3(400, 4, 4), blk, 0, stream>>>(nullptr, 2, 64, nullptr, 0, 0, 110592, 2, b_co, nullptr, 4, 216, 0);
  dcn_k<<<dim3(800, 4), blk, 0, stream>>>(nbr, 0, 0, b_dcn, nullptr, 3);
  // cascade
  conv_mfma<<<dim3(400, 1, 4), blk, 0, stream>>>(nullptr, 3, 64, ref, 0, 64, 258048, 4, b_coff1, nullptr, 1, 64, 1);
  conv_mfma<<<dim3(400, 1, 4), blk, 0, stream>>>(nullptr, 1, 64, nullptr, 0, 0, 331776, 2, b_coff2, nullptr, 2, 64, 1);
  conv_mfma<<<dim3(400, 4, 4), blk, 0, stream>>>(nullptr, 2, 64, nullptr, 0, 0, 368640, 2, b_cco, nullptr, 4, 216, 0);
  dcn_k<<<dim3(800, 4), blk, 0, stream>>>(nullptr, 3, 41472, b_cdcn, out, 0);
}

// Round 7
// 1018.753 us; speedup vs baseline: 2.7494x; 1.2832x over previous
//
#include <hip/hip_runtime.h>
#include <hip/hip_bf16.h>
#include <stdint.h>

#define B_ 4
#define H_ 160
#define W_ 160
#define HW_ 25600

typedef __hip_bfloat16 bf16;
typedef __attribute__((ext_vector_type(8))) short bf16x8;   // 8 bf16 = 4 VGPRs
typedef __attribute__((ext_vector_type(4))) float f32x4;

// ---------------- static workspace (module .bss) ----------------
__device__ float g_A1[6553600];     // (4,64,160,160) / NHWC xT for dcn1
__device__ float g_A2[6553600];     // (4,64,160,160) / NHWC xT for dcn2
__device__ float g_F1[6553600];
__device__ float g_CO[22118400];    // (4,216,160,160)
__device__ __align__(16) bf16 g_WB[516096];  // conv weights, B-fragment order
__device__ __align__(16) bf16 g_WD[73728];   // 2 x dcn weights, B-frag order, K-permuted

// buffer ids: 0 = use passed pointer, 1=A1, 2=A2, 3=F1, 4=CO
__device__ __forceinline__ const float* rsrc(const float* p, int id) {
  if (id == 1) return g_A1;
  if (id == 2) return g_A2;
  if (id == 3) return g_F1;
  if (id == 4) return g_CO;
  return p;
}
__device__ __forceinline__ float* rdst(float* p, int id) {
  if (id == 1) return g_A1;
  if (id == 2) return g_A2;
  if (id == 3) return g_F1;
  if (id == 4) return g_CO;
  return p;
}

// ---------------- weight prep: conv B-fragment order ----------------
__global__ void prep_wfrag(const float* __restrict__ src, int off,
                           int OC, int CIN, int NB) {
  int i = blockIdx.x * 256 + threadIdx.x;
  int CC = CIN >> 5;
  int total = NB * CC * 18432;
  if (i >= total) return;
  int j = i & 7;
  int t = i >> 3;
  int lane = t & 63; t >>= 6;
  int nt = t & 3; t >>= 2;
  int tap = t % 9; t /= 9;
  int cc = t % CC; int nb = t / CC;
  int oc = nb * 64 + nt * 16 + (lane & 15);
  int ci = cc * 32 + (lane >> 4) * 8 + j;
  float v = (oc < OC) ? src[(oc * CIN + ci) * 9 + tap] : 0.f;
  g_WB[off + i] = __float2bfloat16(v);
}

// dcn weights -> B-frag order with K-permutation k' = g*72 + kk*8 + c
// layout: [kc(18)][nt(4)][lane(64)][j(8)]; oc = nt*16+(lane&15), k' = kc*32+(lane>>4)*8+j
__global__ void prep_wdcnfrag(const float* __restrict__ src, int off) {
  int i = blockIdx.x * 256 + threadIdx.x;
  if (i >= 36864) return;
  int j = i & 7;
  int t = i >> 3;
  int lane = t & 63; t >>= 6;
  int nt = t & 3; int kc = t >> 2;
  int kp = kc * 32 + (lane >> 4) * 8 + j;
  int oc = nt * 16 + (lane & 15);
  int g = kp / 72, r = kp - g * 72;
  int kk = r >> 3, c = r & 7;
  g_WD[off + i] = __float2bfloat16(src[oc * 576 + g * 72 + c * 9 + kk]);
}

// ---------------- NCHW -> NHWC transpose (64 ch) ----------------
// grid (400, B): 64 px x 64 c per block
__global__ __launch_bounds__(256)
void nchw2nhwc(const float* inp, int in_id, float* outp, int out_id) {
  const float* in = rsrc(inp, in_id);
  float* out = rdst(outp, out_id);
  __shared__ float T[64][65];
  int tid = threadIdx.x;
  int px0 = blockIdx.x * 64;
  int b = blockIdx.y;
#pragma unroll
  for (int it = 0; it < 16; ++it) {
    int idx = it * 256 + tid;
    int c = idx >> 6, px = idx & 63;
    T[c][px] = in[(b * 64 + c) * HW_ + px0 + px];
  }
  __syncthreads();
#pragma unroll
  for (int it = 0; it < 16; ++it) {
    int idx = it * 256 + tid;
    int px = idx >> 6, c = idx & 63;
    out[(b * HW_ + px0 + px) * 64 + c] = T[c][px];
  }
}

// ---------------- MFMA conv3x3, pad=1 (unchanged from R6) ----------------
__global__ __launch_bounds__(256)
void conv_mfma(const float* in1p, int id1, int c1,
               const float* in2p, int id2, int c2,
               int woff, int CC, const float* __restrict__ bias,
               float* outp, int out_id, int OC, int act)
{
  const float* in1 = rsrc(in1p, id1);
  const float* in2 = rsrc(in2p, id2);
  float* out = rdst(outp, out_id);

  __shared__ __align__(16) bf16 XS[5440];   // [4 rows][34 cols][ci pad 40]
  __shared__ float OS[4224];                // [64 oc][66]

  int tid = threadIdx.x;
  int bx = blockIdx.x;
  int r0 = 2 * (bx / 5), c0 = 32 * (bx % 5);
  int nb = blockIdx.y;
  int b = blockIdx.z;
  const bf16* wblk = g_WB + woff + nb * CC * 18432;

  int w = tid >> 6;
  int L = tid & 63;
  int lm = L & 15;
  int k0 = (L >> 4) * 8;
  int mrow = w >> 1;
  int mcolb = (w & 1) * 16;

  f32x4 acc[4];
#pragma unroll
  for (int nt = 0; nt < 4; ++nt) acc[nt] = (f32x4)0.f;

  for (int cc = 0; cc < CC; ++cc) {
    int cb = cc * 32;
    __syncthreads();
    {
      int colm = 1 + (tid & 31);
      int sub = tid >> 5;
#pragma unroll
      for (int t = 0; t < 16; ++t) {
        int idx = t * 8 + sub;
        int ci = idx & 31, row = idx >> 5;
        int gy = r0 - 1 + row;
        int gx = c0 + (tid & 31);
        int gc = cb + ci;
        float v = 0.f;
        if (gy >= 0 && gy < H_) {
          v = (gc < c1) ? in1[((b * c1 + gc) * H_ + gy) * W_ + gx]
                        : in2[((b * c2 + gc - c1) * H_ + gy) * W_ + gx];
        }
        XS[(row * 34 + colm) * 40 + ci] = __float2bfloat16(v);
      }
      int hc = (tid & 1) * 33;
      int idx2 = tid >> 1;
      int ci = idx2 & 31, row = idx2 >> 5;
      int gy = r0 - 1 + row;
      int gx = c0 - 1 + hc;
      int gc = cb + ci;
      float v = 0.f;
      if (gy >= 0 && gy < H_ && gx >= 0 && gx < W_) {
        v = (gc < c1) ? in1[((b * c1 + gc) * H_ + gy) * W_ + gx]
                      : in2[((b * c2 + gc - c1) * H_ + gy) * W_ + gx];
      }
      XS[(row * 34 + hc) * 40 + ci] = __float2bfloat16(v);
    }
    __syncthreads();
#pragma unroll 3
    for (int tap = 0; tap < 9; ++tap) {
      int dyp = tap / 3, dxp = tap - dyp * 3;
      bf16x8 a = *(const bf16x8*)&XS[((mrow + dyp) * 34 + mcolb + lm + dxp) * 40 + k0];
      const bf16* wb = wblk + (cc * 9 + tap) * 2048 + L * 8;
#pragma unroll
      for (int nt = 0; nt < 4; ++nt) {
        bf16x8 bf = *(const bf16x8*)(wb + nt * 512);
        acc[nt] = __builtin_amdgcn_mfma_f32_16x16x32_bf16(a, bf, acc[nt], 0, 0, 0);
      }
    }
  }

  __syncthreads();
#pragma unroll
  for (int nt = 0; nt < 4; ++nt)
#pragma unroll
    for (int r = 0; r < 4; ++r) {
      int oc_l = nt * 16 + lm;
      int m = w * 16 + (L >> 4) * 4 + r;
      OS[oc_l * 66 + m] = acc[nt][r];
    }
  __syncthreads();
  for (int i = tid; i < 4096; i += 256) {
    int oc_l = i >> 6, m = i & 63;
    int oc = nb * 64 + oc_l;
    if (oc < OC) {
      float v = OS[oc_l * 66 + m] + bias[oc];
      if (act) v = v > 0.f ? v : 0.1f * v;
      int py = r0 + (m >> 5), px = c0 + (m & 31);
      out[((b * OC + oc) * H_ + py) * W_ + px] = v;
    }
  }
}

// ---------------- fused modulated deformable conv, MFMA phase B ----------------
// grid: (800 = H x W/32, B). block 256 = 4 waves. 32 px x 64 oc per block.
// x input is NHWC (b,H,W,64). vS K-order: k' = g*72 + kk*8 + c, px-stride 584.
__global__ __launch_bounds__(256)
void dcn_k(const float* xp, int x_id,
           int wd_off, const float* __restrict__ bias,
           float* outp, int out_id)
{
  const float* xT = rsrc(xp, x_id);
  const float* co = g_CO;                       // (B,216,H,W)
  const bf16* WD = g_WD + wd_off;               // frag layout [18][4][64][8]
  float* out = rdst(outp, out_id);
  __shared__ __align__(16) bf16 vS[32 * 584];   // 37376 B
  int tid = threadIdx.x;
  int b = blockIdx.y;
  int h = blockIdx.x / 5;
  int w0 = (blockIdx.x % 5) * 32;
  const float* xb = xT + (size_t)b * HW_ * 64;

  // ---- phase A: sample 32px x 8g x 9kk, 8 ch each -> vS ----
  const float* cob = co + ((size_t)b * 216 * HW_) + h * W_ + w0;
#pragma unroll
  for (int t = 0; t < 9; ++t) {
    int idx = t * 256 + tid;      // 72 gk x 32 px
    int gk = idx >> 5;
    int p = idx & 31;
    int g = gk / 9, kk = gk - g * 9;
    float offy = cob[(gk * 2) * HW_ + p];
    float offx = cob[(gk * 2 + 1) * HW_ + p];
    float mval = cob[(144 + gk) * HW_ + p];
    float mask = 1.f / (1.f + __expf(-mval));
    float pyf = offy + (float)(kk / 3 - 1 + h);
    float pxf = offx + (float)(kk % 3 - 1 + w0 + p);
    float y0f = floorf(pyf), x0f = floorf(pxf);
    float ly = pyf - y0f, lx = pxf - x0f;
    int iy0 = (int)y0f, ix0 = (int)x0f;
    int iy1 = iy0 + 1, ix1 = ix0 + 1;
    float w00 = (1.f - ly) * (1.f - lx) * mask;
    float w01 = (1.f - ly) * lx * mask;
    float w10 = ly * (1.f - lx) * mask;
    float w11 = ly * lx * mask;
    if (iy0 < 0 || iy0 >= H_) { w00 = 0.f; w01 = 0.f; }
    if (iy1 < 0 || iy1 >= H_) { w10 = 0.f; w11 = 0.f; }
    if (ix0 < 0 || ix0 >= W_) { w00 = 0.f; w10 = 0.f; }
    if (ix1 < 0 || ix1 >= W_) { w01 = 0.f; w11 = 0.f; }
    int cy0 = min(max(iy0, 0), H_ - 1), cy1 = min(max(iy1, 0), H_ - 1);
    int cx0 = min(max(ix0, 0), W_ - 1), cx1 = min(max(ix1, 0), W_ - 1);
    int gb = g * 8;
    const float4* p00 = (const float4*)(xb + (cy0 * W_ + cx0) * 64 + gb);
    const float4* p01 = (const float4*)(xb + (cy0 * W_ + cx1) * 64 + gb);
    const float4* p10 = (const float4*)(xb + (cy1 * W_ + cx0) * 64 + gb);
    const float4* p11 = (const float4*)(xb + (cy1 * W_ + cx1) * 64 + gb);
    float4 a0 = p00[0], a1 = p00[1];
    float4 b0 = p01[0], b1 = p01[1];
    float4 c0 = p10[0], c1 = p10[1];
    float4 d0 = p11[0], d1 = p11[1];
    float C00[8] = {a0.x,a0.y,a0.z,a0.w,a1.x,a1.y,a1.z,a1.w};
    float C01[8] = {b0.x,b0.y,b0.z,b0.w,b1.x,b1.y,b1.z,b1.w};
    float C10[8] = {c0.x,c0.y,c0.z,c0.w,c1.x,c1.y,c1.z,c1.w};
    float C11[8] = {d0.x,d0.y,d0.z,d0.w,d1.x,d1.y,d1.z,d1.w};
    bf16 tmp[8];
#pragma unroll
    for (int c = 0; c < 8; ++c) {
      float v = w00 * C00[c] + w01 * C01[c] + w10 * C10[c] + w11 * C11[c];
      tmp[c] = __float2bfloat16(v);
    }
    *(uint4*)&vS[p * 584 + g * 72 + kk * 8] = *(const uint4*)tmp;
  }
  __syncthreads();

  // ---- phase B: MFMA. out[32px][64oc] = vS[32][576] x W[576][64] ----
  int w = tid >> 6;
  int L = tid & 63;
  int lm = L & 15;
  int k0 = (L >> 4) * 8;
  int mt = w & 1;            // m-tile (px group of 16)
  int nb2 = (w >> 1) * 2;    // first of 2 n-tiles
  f32x4 acc2[2];
  acc2[0] = (f32x4)0.f; acc2[1] = (f32x4)0.f;
#pragma unroll 3
  for (int kc = 0; kc < 18; ++kc) {
    bf16x8 a = *(const bf16x8*)&vS[(mt * 16 + lm) * 584 + kc * 32 + k0];
#pragma unroll
    for (int i = 0; i < 2; ++i) {
      bf16x8 bw = *(const bf16x8*)(WD + ((kc * 4 + nb2 + i) * 64 + L) * 8);
      acc2[i] = __builtin_amdgcn_mfma_f32_16x16x32_bf16(a, bw, acc2[i], 0, 0, 0);
    }
  }
  __syncthreads();

  // ---- epilogue through LDS (reuse vS) ----
  float* outS = (float*)vS;          // [64 oc][33]
#pragma unroll
  for (int i = 0; i < 2; ++i)
#pragma unroll
    for (int r = 0; r < 4; ++r) {
      int oc = (nb2 + i) * 16 + lm;
      int px = mt * 16 + (L >> 4) * 4 + r;
      outS[oc * 33 + px] = acc2[i][r];
    }
  __syncthreads();
  for (int i = tid; i < 2048; i += 256) {
    int oc = i >> 5, p2 = i & 31;
    float v = outS[oc * 33 + p2] + bias[oc];
    v = v > 0.f ? v : 0.1f * v;
    int oi = ((b * 64 + oc) * H_ + h) * W_ + w0 + p2;
    out[oi] = v;
  }
}

extern "C" void kernel_launch(void* const* d_in, const int* in_sizes, int n_in,
                              void* d_out, int out_size, void* d_ws, size_t ws_size,
                              hipStream_t stream) {
  (void)in_sizes; (void)n_in; (void)out_size; (void)d_ws; (void)ws_size;
  const float* nbr    = (const float*)d_in[0];
  const float* ref    = (const float*)d_in[1];
  const float* w_off1 = (const float*)d_in[2];
  const float* b_off1 = (const float*)d_in[3];
  const float* w_off2 = (const float*)d_in[4];
  const float* b_off2 = (const float*)d_in[5];
  const float* w_co   = (const float*)d_in[6];
  const float* b_co   = (const float*)d_in[7];
  const float* w_dcn  = (const float*)d_in[8];
  const float* b_dcn  = (const float*)d_in[9];
  const float* w_coff1= (const float*)d_in[10];
  const float* b_coff1= (const float*)d_in[11];
  const float* w_coff2= (const float*)d_in[12];
  const float* b_coff2= (const float*)d_in[13];
  const float* w_cco  = (const float*)d_in[14];
  const float* b_cco  = (const float*)d_in[15];
  const float* w_cdcn = (const float*)d_in[16];
  const float* b_cdcn = (const float*)d_in[17];

  prep_wfrag<<<288, 256, 0, stream>>>(w_off1, 0, 64, 128, 1);
  prep_wfrag<<<144, 256, 0, stream>>>(w_off2, 73728, 64, 64, 1);
  prep_wfrag<<<576, 256, 0, stream>>>(w_co, 110592, 216, 64, 4);
  prep_wfrag<<<288, 256, 0, stream>>>(w_coff1, 258048, 64, 128, 1);
  prep_wfrag<<<144, 256, 0, stream>>>(w_coff2, 331776, 64, 64, 1);
  prep_wfrag<<<576, 256, 0, stream>>>(w_cco, 368640, 216, 64, 4);
  prep_wdcnfrag<<<144, 256, 0, stream>>>(w_dcn, 0);
  prep_wdcnfrag<<<144, 256, 0, stream>>>(w_cdcn, 36864);

  dim3 blk(256);
  float* out = (float*)d_out;
  // A1 = lrelu(conv(cat(nbr,ref))); A2 = lrelu(conv(A1))
  conv_mfma<<<dim3(400, 1, 4), blk, 0, stream>>>(nbr, 0, 64, ref, 0, 64, 0, 4, b_off1, nullptr, 1, 64, 1);
  conv_mfma<<<dim3(400, 1, 4), blk, 0, stream>>>(nullptr, 1, 64, nullptr, 0, 0, 73728, 2, b_off2, nullptr, 2, 64, 1);
  // xT1 = NHWC(nbr) -> A1 (A1 now dead); CO = conv(A2); F1 = lrelu(dcn(xT1, CO))
  nchw2nhwc<<<dim3(400, 4), blk, 0, stream>>>(nbr, 0, nullptr, 1);
  conv_mfma<<<dim3(400, 4, 4), blk, 0, stream>>>(nullptr, 2, 64, nullptr, 0, 0, 110592, 2, b_co, nullptr, 4, 216, 0);
  dcn_k<<<dim3(800, 4), blk, 0, stream>>>(nullptr, 1, 0, b_dcn, nullptr, 3);
  // cascade
  conv_mfma<<<dim3(400, 1, 4), blk, 0, stream>>>(nullptr, 3, 64, ref, 0, 64, 258048, 4, b_coff1, nullptr, 1, 64, 1);
  conv_mfma<<<dim3(400, 1, 4), blk, 0, stream>>>(nullptr, 1, 64, nullptr, 0, 0, 331776, 2, b_coff2, nullptr, 2, 64, 1);
  conv_mfma<<<dim3(400, 4, 4), blk, 0, stream>>>(nullptr, 2, 64, nullptr, 0, 0, 368640, 2, b_cco, nullptr, 4, 216, 0);
  // xT2 = NHWC(F1) -> A2 (A2 dead after conv_co2); out = lrelu(dcn(xT2, CO))
  nchw2nhwc<<<dim3(400, 4), blk, 0, stream>>>(nullptr, 3, nullptr, 2);
  dcn_k<<<dim3(800, 4), blk, 0, stream>>>(nullptr, 2, 36864, b_cdcn, out, 0);
}

// Round 8
// 851.019 us; speedup vs baseline: 3.2913x; 1.1971x over previous
//
#include <hip/hip_runtime.h>
#include <hip/hip_bf16.h>
#include <stdint.h>

#define B_ 4
#define H_ 160
#define W_ 160
#define HW_ 25600

typedef __hip_bfloat16 bf16;
typedef __attribute__((ext_vector_type(8))) short bf16x8;
typedef __attribute__((ext_vector_type(4))) float f32x4;

// ---------------- static workspace (module .bss) ----------------
__device__ float g_A1[6553600];     // (4,64,160,160) / NHWC xT for dcn1
__device__ float g_A2[6553600];     // (4,64,160,160) / NHWC xT for dcn2
__device__ float g_F1[6553600];
__device__ float g_CO[22118400];    // (4,216,160,160); mask channels pre-sigmoided
__device__ __align__(16) bf16 g_WB[516096];  // conv weights, B-fragment order
__device__ __align__(16) bf16 g_WD[73728];   // 2 x dcn weights, B-frag order, K-permuted

__device__ __forceinline__ const float* rsrc(const float* p, int id) {
  if (id == 1) return g_A1;
  if (id == 2) return g_A2;
  if (id == 3) return g_F1;
  if (id == 4) return g_CO;
  return p;
}
__device__ __forceinline__ float* rdst(float* p, int id) {
  if (id == 1) return g_A1;
  if (id == 2) return g_A2;
  if (id == 3) return g_F1;
  if (id == 4) return g_CO;
  return p;
}

// ---------------- weight prep: conv B-fragment order ----------------
// layout [nb][cc][tap][nt(NTPB)][lane(64)][j(8)]
__global__ void prep_wfrag(const float* __restrict__ src, int off,
                           int OC, int CIN, int NB, int NTPB) {
  int i = blockIdx.x * 256 + threadIdx.x;
  int CC = CIN >> 5;
  int total = NB * CC * 9 * NTPB * 512;
  if (i >= total) return;
  int j = i & 7;
  int t = i >> 3;
  int lane = t & 63; t >>= 6;
  int nt = t % NTPB; t /= NTPB;
  int tap = t % 9; t /= 9;
  int cc = t % CC; int nb = t / CC;
  int oc = nb * (NTPB * 16) + nt * 16 + (lane & 15);
  int ci = cc * 32 + (lane >> 4) * 8 + j;
  float v = (oc < OC) ? src[(oc * CIN + ci) * 9 + tap] : 0.f;
  g_WB[off + i] = __float2bfloat16(v);
}

// dcn weights -> B-frag order with K-permutation k' = g*72 + kk*8 + c
__global__ void prep_wdcnfrag(const float* __restrict__ src, int off) {
  int i = blockIdx.x * 256 + threadIdx.x;
  if (i >= 36864) return;
  int j = i & 7;
  int t = i >> 3;
  int lane = t & 63; t >>= 6;
  int nt = t & 3; int kc = t >> 2;
  int kp = kc * 32 + (lane >> 4) * 8 + j;
  int oc = nt * 16 + (lane & 15);
  int g = kp / 72, r = kp - g * 72;
  int kk = r >> 3, c = r & 7;
  g_WD[off + i] = __float2bfloat16(src[oc * 576 + g * 72 + c * 9 + kk]);
}

// ---------------- NCHW -> NHWC transpose (64 ch) ----------------
__global__ __launch_bounds__(256)
void nchw2nhwc(const float* inp, int in_id, float* outp, int out_id) {
  const float* in = rsrc(inp, in_id);
  float* out = rdst(outp, out_id);
  __shared__ float T[64][65];
  int tid = threadIdx.x;
  int px0 = blockIdx.x * 64;
  int b = blockIdx.y;
#pragma unroll
  for (int it = 0; it < 16; ++it) {
    int idx = it * 256 + tid;
    int c = idx >> 6, px = idx & 63;
    T[c][px] = in[(b * 64 + c) * HW_ + px0 + px];
  }
  __syncthreads();
#pragma unroll
  for (int it = 0; it < 16; ++it) {
    int idx = it * 256 + tid;
    int px = idx >> 6, c = idx & 63;
    out[(b * HW_ + px0 + px) * 64 + c] = T[c][px];
  }
}

// ---------------- MFMA conv3x3, pad=1, 4x32 px x NT*16 oc per block ----------------
// grid: (200 = 40 row-quads x 5 col-tiles, NB, B). block 256 = 4 waves.
// act: 0 none, 1 lrelu, 2 sigmoid on oc>=144
template<int NT>
__global__ __launch_bounds__(256)
void conv_mfma(const float* in1p, int id1, int c1,
               const float* in2p, int id2, int c2,
               int woff, int CC, const float* __restrict__ bias,
               float* outp, int out_id, int OC, int act)
{
  const float* in1 = rsrc(in1p, id1);
  const float* in2 = rsrc(in2p, id2);
  float* out = rdst(outp, out_id);

  constexpr int XS_BYTES = 6 * 34 * 40 * 2;        // 16320
  constexpr int OS_BYTES = NT * 16 * 66 * 4;
  constexpr int SH_BYTES = (OS_BYTES > XS_BYTES) ? OS_BYTES : XS_BYTES;
  __shared__ __align__(16) char SH[SH_BYTES];
  bf16* XS = (bf16*)SH;         // [6 rows][34 cols][ci pad 40]
  float* OS = (float*)SH;       // [NT*16 oc][66]

  int tid = threadIdx.x;
  int bx = blockIdx.x;
  int r0 = 4 * (bx / 5), c0 = 32 * (bx % 5);
  int nb = blockIdx.y;
  int b = blockIdx.z;

  int w = tid >> 6;
  int L = tid & 63;
  int lm = L & 15;
  int k0 = (L >> 4) * 8;

  f32x4 acc[2][NT];
#pragma unroll
  for (int mi = 0; mi < 2; ++mi)
#pragma unroll
    for (int nt = 0; nt < NT; ++nt) acc[mi][nt] = (f32x4)0.f;

  for (int cc = 0; cc < CC; ++cc) {
    int cb = cc * 32;
    __syncthreads();
    // interior: 6 rows x cols 1..32 x 32 ci, float2 per thread per round
    {
      int colp = tid & 15, rr = tid >> 4;
      int gx = c0 + 2 * colp;
#pragma unroll
      for (int t = 0; t < 12; ++t) {
        int rc2 = t * 16 + rr;
        int row = rc2 >> 5, ci = rc2 & 31;
        int gy = r0 - 1 + row;
        int gc = cb + ci;
        float2 v = make_float2(0.f, 0.f);
        if (gy >= 0 && gy < H_) {
          const float* src = (gc < c1) ? &in1[((b * c1 + gc) * H_ + gy) * W_ + gx]
                                       : &in2[((b * c2 + gc - c1) * H_ + gy) * W_ + gx];
          v = *(const float2*)src;
        }
        int base = (row * 34 + 1 + 2 * colp) * 40 + ci;
        XS[base] = __float2bfloat16(v.x);
        XS[base + 40] = __float2bfloat16(v.y);
      }
      // halo cols 0, 33
#pragma unroll
      for (int t = 0; t < 2; ++t) {
        int id = t * 256 + tid;
        if (id < 384) {
          int ci = id & 31, rc = id >> 5;
          int row = rc >> 1, col = (rc & 1) * 33;
          int gy = r0 - 1 + row, gxh = c0 - 1 + col;
          int gc = cb + ci;
          float v = 0.f;
          if (gy >= 0 && gy < H_ && gxh >= 0 && gxh < W_)
            v = (gc < c1) ? in1[((b * c1 + gc) * H_ + gy) * W_ + gxh]
                          : in2[((b * c2 + gc - c1) * H_ + gy) * W_ + gxh];
          XS[(row * 34 + col) * 40 + ci] = __float2bfloat16(v);
        }
      }
    }
    __syncthreads();
    const bf16* wcc = g_WB + woff + ((size_t)nb * CC + cc) * (9 * NT * 512);
#pragma unroll
    for (int tap = 0; tap < 9; ++tap) {
      int dy = tap / 3, dx = tap - dy * 3;
      bf16x8 a0 = *(const bf16x8*)&XS[((w + dy) * 34 + lm + dx) * 40 + k0];
      bf16x8 a1 = *(const bf16x8*)&XS[((w + dy) * 34 + 16 + lm + dx) * 40 + k0];
      const bf16* wt = wcc + tap * (NT * 512) + L * 8;
#pragma unroll
      for (int nt = 0; nt < NT; ++nt) {
        bf16x8 bw = *(const bf16x8*)(wt + nt * 512);
        acc[0][nt] = __builtin_amdgcn_mfma_f32_16x16x32_bf16(a0, bw, acc[0][nt], 0, 0, 0);
        acc[1][nt] = __builtin_amdgcn_mfma_f32_16x16x32_bf16(a1, bw, acc[1][nt], 0, 0, 0);
      }
    }
  }

  // ---- epilogue: 2 passes of 64 px through LDS (aliases XS) ----
  for (int pass = 0; pass < 2; ++pass) {
    __syncthreads();
    if ((w >> 1) == pass) {
#pragma unroll
      for (int mi = 0; mi < 2; ++mi)
#pragma unroll
        for (int nt = 0; nt < NT; ++nt)
#pragma unroll
          for (int r = 0; r < 4; ++r) {
            int m_local = 32 * (w & 1) + 16 * mi + (L >> 4) * 4 + r;
            OS[(nt * 16 + lm) * 66 + m_local] = acc[mi][nt][r];
          }
    }
    __syncthreads();
    for (int i = tid; i < NT * 1024; i += 256) {
      int oc_l = i >> 6, m = i & 63;
      int oc = nb * (NT * 16) + oc_l;
      if (oc < OC) {
        float v = OS[oc_l * 66 + m] + bias[oc];
        if (act == 1) v = v > 0.f ? v : 0.1f * v;
        else if (act == 2 && oc >= 144) v = 1.f / (1.f + __expf(-v));
        int px = pass * 64 + m;
        int py = r0 + (px >> 5), pxc = c0 + (px & 31);
        out[((b * OC + oc) * H_ + py) * W_ + pxc] = v;
      }
    }
  }
}

// ---------------- fused modulated deformable conv, MFMA phase B ----------------
// grid: (800, B). block 256. 32 px x 64 oc. x is NHWC. CO mask pre-sigmoided.
__global__ __launch_bounds__(256)
void dcn_k(const float* xp, int x_id,
           int wd_off, const float* __restrict__ bias,
           float* outp, int out_id)
{
  const float* xT = rsrc(xp, x_id);
  const float* co = g_CO;
  const bf16* WD = g_WD + wd_off;               // [18][4][64][8]
  float* out = rdst(outp, out_id);
  __shared__ __align__(16) bf16 vS[32 * 584];
  int tid = threadIdx.x;
  int b = blockIdx.y;
  int h = blockIdx.x / 5;
  int w0 = (blockIdx.x % 5) * 32;
  const float* xb = xT + (size_t)b * HW_ * 64;

  const float* cob = co + ((size_t)b * 216 * HW_) + h * W_ + w0;
#pragma unroll
  for (int t = 0; t < 9; ++t) {
    int idx = t * 256 + tid;
    int gk = idx >> 5;
    int p = idx & 31;
    int g = gk / 9, kk = gk - g * 9;
    float offy = cob[(gk * 2) * HW_ + p];
    float offx = cob[(gk * 2 + 1) * HW_ + p];
    float mask = cob[(144 + gk) * HW_ + p];    // already sigmoided
    float pyf = offy + (float)(kk / 3 - 1 + h);
    float pxf = offx + (float)(kk % 3 - 1 + w0 + p);
    float y0f = floorf(pyf), x0f = floorf(pxf);
    float ly = pyf - y0f, lx = pxf - x0f;
    int iy0 = (int)y0f, ix0 = (int)x0f;
    int iy1 = iy0 + 1, ix1 = ix0 + 1;
    float w00 = (1.f - ly) * (1.f - lx) * mask;
    float w01 = (1.f - ly) * lx * mask;
    float w10 = ly * (1.f - lx) * mask;
    float w11 = ly * lx * mask;
    if (iy0 < 0 || iy0 >= H_) { w00 = 0.f; w01 = 0.f; }
    if (iy1 < 0 || iy1 >= H_) { w10 = 0.f; w11 = 0.f; }
    if (ix0 < 0 || ix0 >= W_) { w00 = 0.f; w10 = 0.f; }
    if (ix1 < 0 || ix1 >= W_) { w01 = 0.f; w11 = 0.f; }
    int cy0 = min(max(iy0, 0), H_ - 1), cy1 = min(max(iy1, 0), H_ - 1);
    int cx0 = min(max(ix0, 0), W_ - 1), cx1 = min(max(ix1, 0), W_ - 1);
    int gb = g * 8;
    const float4* p00 = (const float4*)(xb + (cy0 * W_ + cx0) * 64 + gb);
    const float4* p01 = (const float4*)(xb + (cy0 * W_ + cx1) * 64 + gb);
    const float4* p10 = (const float4*)(xb + (cy1 * W_ + cx0) * 64 + gb);
    const float4* p11 = (const float4*)(xb + (cy1 * W_ + cx1) * 64 + gb);
    float4 a0 = p00[0], a1 = p00[1];
    float4 b0 = p01[0], b1 = p01[1];
    float4 c0 = p10[0], c1 = p10[1];
    float4 d0 = p11[0], d1 = p11[1];
    float C00[8] = {a0.x,a0.y,a0.z,a0.w,a1.x,a1.y,a1.z,a1.w};
    float C01[8] = {b0.x,b0.y,b0.z,b0.w,b1.x,b1.y,b1.z,b1.w};
    float C10[8] = {c0.x,c0.y,c0.z,c0.w,c1.x,c1.y,c1.z,c1.w};
    float C11[8] = {d0.x,d0.y,d0.z,d0.w,d1.x,d1.y,d1.z,d1.w};
    bf16 tmp[8];
#pragma unroll
    for (int c = 0; c < 8; ++c) {
      float v = w00 * C00[c] + w01 * C01[c] + w10 * C10[c] + w11 * C11[c];
      tmp[c] = __float2bfloat16(v);
    }
    *(uint4*)&vS[p * 584 + g * 72 + kk * 8] = *(const uint4*)tmp;
  }
  __syncthreads();

  int w = tid >> 6;
  int L = tid & 63;
  int lm = L & 15;
  int k0 = (L >> 4) * 8;
  int mt = w & 1;
  int nb2 = (w >> 1) * 2;
  f32x4 acc2[2];
  acc2[0] = (f32x4)0.f; acc2[1] = (f32x4)0.f;
#pragma unroll 3
  for (int kc = 0; kc < 18; ++kc) {
    bf16x8 a = *(const bf16x8*)&vS[(mt * 16 + lm) * 584 + kc * 32 + k0];
#pragma unroll
    for (int i = 0; i < 2; ++i) {
      bf16x8 bw = *(const bf16x8*)(WD + ((kc * 4 + nb2 + i) * 64 + L) * 8);
      acc2[i] = __builtin_amdgcn_mfma_f32_16x16x32_bf16(a, bw, acc2[i], 0, 0, 0);
    }
  }
  __syncthreads();

  float* outS = (float*)vS;
#pragma unroll
  for (int i = 0; i < 2; ++i)
#pragma unroll
    for (int r = 0; r < 4; ++r) {
      int oc = (nb2 + i) * 16 + lm;
      int px = mt * 16 + (L >> 4) * 4 + r;
      outS[oc * 33 + px] = acc2[i][r];
    }
  __syncthreads();
  for (int i = tid; i < 2048; i += 256) {
    int oc = i >> 5, p2 = i & 31;
    float v = outS[oc * 33 + p2] + bias[oc];
    v = v > 0.f ? v : 0.1f * v;
    int oi = ((b * 64 + oc) * H_ + h) * W_ + w0 + p2;
    out[oi] = v;
  }
}

extern "C" void kernel_launch(void* const* d_in, const int* in_sizes, int n_in,
                              void* d_out, int out_size, void* d_ws, size_t ws_size,
                              hipStream_t stream) {
  (void)in_sizes; (void)n_in; (void)out_size; (void)d_ws; (void)ws_size;
  const float* nbr    = (const float*)d_in[0];
  const float* ref    = (const float*)d_in[1];
  const float* w_off1 = (const float*)d_in[2];
  const float* b_off1 = (const float*)d_in[3];
  const float* w_off2 = (const float*)d_in[4];
  const float* b_off2 = (const float*)d_in[5];
  const float* w_co   = (const float*)d_in[6];
  const float* b_co   = (const float*)d_in[7];
  const float* w_dcn  = (const float*)d_in[8];
  const float* b_dcn  = (const float*)d_in[9];
  const float* w_coff1= (const float*)d_in[10];
  const float* b_coff1= (const float*)d_in[11];
  const float* w_coff2= (const float*)d_in[12];
  const float* b_coff2= (const float*)d_in[13];
  const float* w_cco  = (const float*)d_in[14];
  const float* b_cco  = (const float*)d_in[15];
  const float* w_cdcn = (const float*)d_in[16];
  const float* b_cdcn = (const float*)d_in[17];

  // g_WB offsets (bf16): w1=0 (73728), w2=73728 (36864), wco=110592 (129024),
  //                      wc1=239616, wc2=313344, wcco=350208; total 479232
  prep_wfrag<<<288, 256, 0, stream>>>(w_off1, 0, 64, 128, 1, 4);
  prep_wfrag<<<144, 256, 0, stream>>>(w_off2, 73728, 64, 64, 1, 4);
  prep_wfrag<<<504, 256, 0, stream>>>(w_co, 110592, 216, 64, 2, 7);
  prep_wfrag<<<288, 256, 0, stream>>>(w_coff1, 239616, 64, 128, 1, 4);
  prep_wfrag<<<144, 256, 0, stream>>>(w_coff2, 313344, 64, 64, 1, 4);
  prep_wfrag<<<504, 256, 0, stream>>>(w_cco, 350208, 216, 64, 2, 7);
  prep_wdcnfrag<<<144, 256, 0, stream>>>(w_dcn, 0);
  prep_wdcnfrag<<<144, 256, 0, stream>>>(w_cdcn, 36864);

  dim3 blk(256);
  float* out = (float*)d_out;
  // A1 = lrelu(conv(cat(nbr,ref))); A2 = lrelu(conv(A1))
  conv_mfma<4><<<dim3(200, 1, 4), blk, 0, stream>>>(nbr, 0, 64, ref, 0, 64, 0, 4, b_off1, nullptr, 1, 64, 1);
  conv_mfma<4><<<dim3(200, 1, 4), blk, 0, stream>>>(nullptr, 1, 64, nullptr, 0, 0, 73728, 2, b_off2, nullptr, 2, 64, 1);
  // xT1 = NHWC(nbr) -> A1; CO = conv(A2) [mask pre-sigmoided]; F1 = lrelu(dcn(xT1, CO))
  nchw2nhwc<<<dim3(400, 4), blk, 0, stream>>>(nbr, 0, nullptr, 1);
  conv_mfma<7><<<dim3(200, 2, 4), blk, 0, stream>>>(nullptr, 2, 64, nullptr, 0, 0, 110592, 2, b_co, nullptr, 4, 216, 2);
  dcn_k<<<dim3(800, 4), blk, 0, stream>>>(nullptr, 1, 0, b_dcn, nullptr, 3);
  // cascade
  conv_mfma<4><<<dim3(200, 1, 4), blk, 0, stream>>>(nullptr, 3, 64, ref, 0, 64, 239616, 4, b_coff1, nullptr, 1, 64, 1);
  conv_mfma<4><<<dim3(200, 1, 4), blk, 0, stream>>>(nullptr, 1, 64, nullptr, 0, 0, 313344, 2, b_coff2, nullptr, 2, 64, 1);
  conv_mfma<7><<<dim3(200, 2, 4), blk, 0, stream>>>(nullptr, 2, 64, nullptr, 0, 0, 350208, 2, b_cco, nullptr, 4, 216, 2);
  nchw2nhwc<<<dim3(400, 4), blk, 0, stream>>>(nullptr, 3, nullptr, 2);
  dcn_k<<<dim3(800, 4), blk, 0, stream>>>(nullptr, 2, 36864, b_cdcn, out, 0);
}

// Round 9
// 801.105 us; speedup vs baseline: 3.4963x; 1.0623x over previous
//
#include <hip/hip_runtime.h>
#include <hip/hip_bf16.h>
#include <stdint.h>

#define B_ 4
#define H_ 160
#define W_ 160
#define HW_ 25600

typedef __hip_bfloat16 bf16;
typedef __attribute__((ext_vector_type(8))) short bf16x8;
typedef __attribute__((ext_vector_type(4))) float f32x4;

// ---------------- static workspace (module .bss) ----------------
__device__ float g_A1[6553600];     // (4,64,160,160) conv scratch
__device__ float g_A2[6553600];
__device__ float g_F1[6553600];
__device__ float g_CO[22118400];    // (4,216,160,160); mask channels pre-sigmoided
__device__ __align__(16) bf16 g_X1[6553600];  // NHWC bf16 x for dcn1
__device__ __align__(16) bf16 g_X2[6553600];  // NHWC bf16 x for dcn2
__device__ __align__(16) bf16 g_WB[516096];   // conv weights, B-fragment order
__device__ __align__(16) bf16 g_WD[73728];    // 2 x dcn weights, B-frag, K-permuted

__device__ __forceinline__ const float* rsrc(const float* p, int id) {
  if (id == 1) return g_A1;
  if (id == 2) return g_A2;
  if (id == 3) return g_F1;
  if (id == 4) return g_CO;
  return p;
}
__device__ __forceinline__ float* rdst(float* p, int id) {
  if (id == 1) return g_A1;
  if (id == 2) return g_A2;
  if (id == 3) return g_F1;
  if (id == 4) return g_CO;
  return p;
}
__device__ __forceinline__ const bf16* xsrc(int id) {
  return (id == 5) ? g_X1 : g_X2;
}
__device__ __forceinline__ bf16* xdst(int id) {
  if (id == 5) return g_X1;
  if (id == 6) return g_X2;
  return nullptr;
}

// ---------------- weight prep: conv B-fragment order ----------------
// layout [nb][cc][tap][nt(NTPB)][lane(64)][j(8)]
__global__ void prep_wfrag(const float* __restrict__ src, int off,
                           int OC, int CIN, int NB, int NTPB) {
  int i = blockIdx.x * 256 + threadIdx.x;
  int CC = CIN >> 5;
  int total = NB * CC * 9 * NTPB * 512;
  if (i >= total) return;
  int j = i & 7;
  int t = i >> 3;
  int lane = t & 63; t >>= 6;
  int nt = t % NTPB; t /= NTPB;
  int tap = t % 9; t /= 9;
  int cc = t % CC; int nb = t / CC;
  int oc = nb * (NTPB * 16) + nt * 16 + (lane & 15);
  int ci = cc * 32 + (lane >> 4) * 8 + j;
  float v = (oc < OC) ? src[(oc * CIN + ci) * 9 + tap] : 0.f;
  g_WB[off + i] = __float2bfloat16(v);
}

// dcn weights -> B-frag order with K-permutation k' = g*72 + kk*8 + c
__global__ void prep_wdcnfrag(const float* __restrict__ src, int off) {
  int i = blockIdx.x * 256 + threadIdx.x;
  if (i >= 36864) return;
  int j = i & 7;
  int t = i >> 3;
  int lane = t & 63; t >>= 6;
  int nt = t & 3; int kc = t >> 2;
  int kp = kc * 32 + (lane >> 4) * 8 + j;
  int oc = nt * 16 + (lane & 15);
  int g = kp / 72, r = kp - g * 72;
  int kk = r >> 3, c = r & 7;
  g_WD[off + i] = __float2bfloat16(src[oc * 576 + g * 72 + c * 9 + kk]);
}

// ---------------- NCHW f32 -> NHWC bf16 transpose (64 ch) ----------------
__global__ __launch_bounds__(256)
void nchw2nhwc_bf(const float* __restrict__ in, int out_id) {
  bf16* out = xdst(out_id);
  __shared__ float T[64][65];
  int tid = threadIdx.x;
  int px0 = blockIdx.x * 64;
  int b = blockIdx.y;
#pragma unroll
  for (int it = 0; it < 16; ++it) {
    int idx = it * 256 + tid;
    int c = idx >> 6, px = idx & 63;
    T[c][px] = in[(b * 64 + c) * HW_ + px0 + px];
  }
  __syncthreads();
#pragma unroll
  for (int it = 0; it < 16; ++it) {
    int idx = it * 256 + tid;
    int px = idx >> 6, c = idx & 63;
    out[((size_t)b * HW_ + px0 + px) * 64 + c] = __float2bfloat16(T[c][px]);
  }
}

// ---------------- MFMA conv3x3, pad=1, 4x32 px x NT*16 oc per block ----------------
// act: 0 none, 1 lrelu, 2 sigmoid on oc>=144
template<int NT>
__global__ __launch_bounds__(256)
void conv_mfma(const float* in1p, int id1, int c1,
               const float* in2p, int id2, int c2,
               int woff, int CC, const float* __restrict__ bias,
               float* outp, int out_id, int OC, int act)
{
  const float* in1 = rsrc(in1p, id1);
  const float* in2 = rsrc(in2p, id2);
  float* out = rdst(outp, out_id);

  constexpr int XS_BYTES = 6 * 34 * 40 * 2;        // 16320
  constexpr int OS_BYTES = NT * 16 * 66 * 4;
  constexpr int SH_BYTES = (OS_BYTES > XS_BYTES) ? OS_BYTES : XS_BYTES;
  __shared__ __align__(16) char SH[SH_BYTES];
  bf16* XS = (bf16*)SH;         // [6 rows][34 cols][ci pad 40]
  float* OS = (float*)SH;       // [NT*16 oc][66]

  int tid = threadIdx.x;
  int bx = blockIdx.x;
  int r0 = 4 * (bx / 5), c0 = 32 * (bx % 5);
  int nb = blockIdx.y;
  int b = blockIdx.z;

  int w = tid >> 6;
  int L = tid & 63;
  int lm = L & 15;
  int k0 = (L >> 4) * 8;

  f32x4 acc[2][NT];
#pragma unroll
  for (int mi = 0; mi < 2; ++mi)
#pragma unroll
    for (int nt = 0; nt < NT; ++nt) acc[mi][nt] = (f32x4)0.f;

  for (int cc = 0; cc < CC; ++cc) {
    int cb = cc * 32;
    __syncthreads();
    {
      int colp = tid & 15, rr = tid >> 4;
      int gx = c0 + 2 * colp;
#pragma unroll
      for (int t = 0; t < 12; ++t) {
        int rc2 = t * 16 + rr;
        int row = rc2 >> 5, ci = rc2 & 31;
        int gy = r0 - 1 + row;
        int gc = cb + ci;
        float2 v = make_float2(0.f, 0.f);
        if (gy >= 0 && gy < H_) {
          const float* src = (gc < c1) ? &in1[((b * c1 + gc) * H_ + gy) * W_ + gx]
                                       : &in2[((b * c2 + gc - c1) * H_ + gy) * W_ + gx];
          v = *(const float2*)src;
        }
        int base = (row * 34 + 1 + 2 * colp) * 40 + ci;
        XS[base] = __float2bfloat16(v.x);
        XS[base + 40] = __float2bfloat16(v.y);
      }
#pragma unroll
      for (int t = 0; t < 2; ++t) {
        int id = t * 256 + tid;
        if (id < 384) {
          int ci = id & 31, rc = id >> 5;
          int row = rc >> 1, col = (rc & 1) * 33;
          int gy = r0 - 1 + row, gxh = c0 - 1 + col;
          int gc = cb + ci;
          float v = 0.f;
          if (gy >= 0 && gy < H_ && gxh >= 0 && gxh < W_)
            v = (gc < c1) ? in1[((b * c1 + gc) * H_ + gy) * W_ + gxh]
                          : in2[((b * c2 + gc - c1) * H_ + gy) * W_ + gxh];
          XS[(row * 34 + col) * 40 + ci] = __float2bfloat16(v);
        }
      }
    }
    __syncthreads();
    const bf16* wcc = g_WB + woff + ((size_t)nb * CC + cc) * (9 * NT * 512);
#pragma unroll
    for (int tap = 0; tap < 9; ++tap) {
      int dy = tap / 3, dx = tap - dy * 3;
      bf16x8 a0 = *(const bf16x8*)&XS[((w + dy) * 34 + lm + dx) * 40 + k0];
      bf16x8 a1 = *(const bf16x8*)&XS[((w + dy) * 34 + 16 + lm + dx) * 40 + k0];
      const bf16* wt = wcc + tap * (NT * 512) + L * 8;
#pragma unroll
      for (int nt = 0; nt < NT; ++nt) {
        bf16x8 bw = *(const bf16x8*)(wt + nt * 512);
        acc[0][nt] = __builtin_amdgcn_mfma_f32_16x16x32_bf16(a0, bw, acc[0][nt], 0, 0, 0);
        acc[1][nt] = __builtin_amdgcn_mfma_f32_16x16x32_bf16(a1, bw, acc[1][nt], 0, 0, 0);
      }
    }
  }

  for (int pass = 0; pass < 2; ++pass) {
    __syncthreads();
    if ((w >> 1) == pass) {
#pragma unroll
      for (int mi = 0; mi < 2; ++mi)
#pragma unroll
        for (int nt = 0; nt < NT; ++nt)
#pragma unroll
          for (int r = 0; r < 4; ++r) {
            int m_local = 32 * (w & 1) + 16 * mi + (L >> 4) * 4 + r;
            OS[(nt * 16 + lm) * 66 + m_local] = acc[mi][nt][r];
          }
    }
    __syncthreads();
    for (int i = tid; i < NT * 1024; i += 256) {
      int oc_l = i >> 6, m = i & 63;
      int oc = nb * (NT * 16) + oc_l;
      if (oc < OC) {
        float v = OS[oc_l * 66 + m] + bias[oc];
        if (act == 1) v = v > 0.f ? v : 0.1f * v;
        else if (act == 2 && oc >= 144) v = 1.f / (1.f + __expf(-v));
        int px = pass * 64 + m;
        int py = r0 + (px >> 5), pxc = c0 + (px & 31);
        out[((b * OC + oc) * H_ + py) * W_ + pxc] = v;
      }
    }
  }
}

// ---------------- fused modulated deformable conv ----------------
// grid: (800, B). block 256. 32 px x 64 oc. x is NHWC bf16. CO mask pre-sigmoided.
// optionally also writes NHWC bf16 copy of output (xt_out_id 5/6, 0 = none).
#define LO16(u) __uint_as_float((u) << 16)
#define HI16(u) __uint_as_float((u) & 0xffff0000u)

__global__ __launch_bounds__(256)
void dcn_k(int x_id, int wd_off, const float* __restrict__ bias,
           float* outp, int out_id, int xt_out_id)
{
  const bf16* xT = xsrc(x_id);
  const float* co = g_CO;
  const bf16* WD = g_WD + wd_off;               // [18][4][64][8]
  float* out = rdst(outp, out_id);
  __shared__ __align__(16) bf16 vS[32 * 584];
  int tid = threadIdx.x;
  int b = blockIdx.y;
  int h = blockIdx.x / 5;
  int w0 = (blockIdx.x % 5) * 32;
  const bf16* xb = xT + (size_t)b * HW_ * 64;

  // ---- phase A: hoisted co loads, then bf16 gathers ----
  const float* cob = co + ((size_t)b * 216 * HW_) + h * W_ + w0;
  float oy[9], ox[9], mk[9];
#pragma unroll
  for (int t = 0; t < 9; ++t) {
    int idx = t * 256 + tid;
    int gk = idx >> 5, p = idx & 31;
    oy[t] = cob[(gk * 2) * HW_ + p];
    ox[t] = cob[(gk * 2 + 1) * HW_ + p];
    mk[t] = cob[(144 + gk) * HW_ + p];   // pre-sigmoided
  }
#pragma unroll
  for (int t = 0; t < 9; ++t) {
    int idx = t * 256 + tid;
    int gk = idx >> 5, p = idx & 31;
    int g = gk / 9, kk = gk - g * 9;
    float pyf = oy[t] + (float)(kk / 3 - 1 + h);
    float pxf = ox[t] + (float)(kk % 3 - 1 + w0 + p);
    float y0f = floorf(pyf), x0f = floorf(pxf);
    float ly = pyf - y0f, lx = pxf - x0f;
    int iy0 = (int)y0f, ix0 = (int)x0f;
    int iy1 = iy0 + 1, ix1 = ix0 + 1;
    float mask = mk[t];
    float w00 = (1.f - ly) * (1.f - lx) * mask;
    float w01 = (1.f - ly) * lx * mask;
    float w10 = ly * (1.f - lx) * mask;
    float w11 = ly * lx * mask;
    if (iy0 < 0 || iy0 >= H_) { w00 = 0.f; w01 = 0.f; }
    if (iy1 < 0 || iy1 >= H_) { w10 = 0.f; w11 = 0.f; }
    if (ix0 < 0 || ix0 >= W_) { w00 = 0.f; w10 = 0.f; }
    if (ix1 < 0 || ix1 >= W_) { w01 = 0.f; w11 = 0.f; }
    int cy0 = min(max(iy0, 0), H_ - 1), cy1 = min(max(iy1, 0), H_ - 1);
    int cx0 = min(max(ix0, 0), W_ - 1), cx1 = min(max(ix1, 0), W_ - 1);
    int gb = g * 8;
    uint4 u00 = *(const uint4*)(xb + (cy0 * W_ + cx0) * 64 + gb);
    uint4 u01 = *(const uint4*)(xb + (cy0 * W_ + cx1) * 64 + gb);
    uint4 u10 = *(const uint4*)(xb + (cy1 * W_ + cx0) * 64 + gb);
    uint4 u11 = *(const uint4*)(xb + (cy1 * W_ + cx1) * 64 + gb);
    bf16 tmp[8];
#define LERP2(ci, A, Bq, Cq, Dq) { \
    float vlo = w00 * LO16(A) + w01 * LO16(Bq) + w10 * LO16(Cq) + w11 * LO16(Dq); \
    float vhi = w00 * HI16(A) + w01 * HI16(Bq) + w10 * HI16(Cq) + w11 * HI16(Dq); \
    tmp[2*(ci)] = __float2bfloat16(vlo); tmp[2*(ci)+1] = __float2bfloat16(vhi); }
    LERP2(0, u00.x, u01.x, u10.x, u11.x);
    LERP2(1, u00.y, u01.y, u10.y, u11.y);
    LERP2(2, u00.z, u01.z, u10.z, u11.z);
    LERP2(3, u00.w, u01.w, u10.w, u11.w);
#undef LERP2
    *(uint4*)&vS[p * 584 + g * 72 + kk * 8] = *(const uint4*)tmp;
  }
  __syncthreads();

  // ---- phase B: MFMA ----
  int w = tid >> 6;
  int L = tid & 63;
  int lm = L & 15;
  int k0 = (L >> 4) * 8;
  int mt = w & 1;
  int nb2 = (w >> 1) * 2;
  f32x4 acc2[2];
  acc2[0] = (f32x4)0.f; acc2[1] = (f32x4)0.f;
#pragma unroll 3
  for (int kc = 0; kc < 18; ++kc) {
    bf16x8 a = *(const bf16x8*)&vS[(mt * 16 + lm) * 584 + kc * 32 + k0];
#pragma unroll
    for (int i = 0; i < 2; ++i) {
      bf16x8 bw = *(const bf16x8*)(WD + ((kc * 4 + nb2 + i) * 64 + L) * 8);
      acc2[i] = __builtin_amdgcn_mfma_f32_16x16x32_bf16(a, bw, acc2[i], 0, 0, 0);
    }
  }
  __syncthreads();

  // ---- epilogue through LDS ----
  float* outS = (float*)vS;          // [64 oc][33]
#pragma unroll
  for (int i = 0; i < 2; ++i)
#pragma unroll
    for (int r = 0; r < 4; ++r) {
      int oc = (nb2 + i) * 16 + lm;
      int px = mt * 16 + (L >> 4) * 4 + r;
      outS[oc * 33 + px] = acc2[i][r];
    }
  __syncthreads();
  for (int i = tid; i < 2048; i += 256) {
    int oc = i >> 5, p2 = i & 31;
    float v = outS[oc * 33 + p2] + bias[oc];
    v = v > 0.f ? v : 0.1f * v;
    int oi = ((b * 64 + oc) * H_ + h) * W_ + w0 + p2;
    out[oi] = v;
  }
  if (xt_out_id) {
    bf16* xt = xdst(xt_out_id);
    for (int i = tid; i < 2048; i += 256) {
      int p2 = i >> 6, c = i & 63;
      float v = outS[c * 33 + p2] + bias[c];
      v = v > 0.f ? v : 0.1f * v;
      xt[((size_t)b * HW_ + h * W_ + w0 + p2) * 64 + c] = __float2bfloat16(v);
    }
  }
}

extern "C" void kernel_launch(void* const* d_in, const int* in_sizes, int n_in,
                              void* d_out, int out_size, void* d_ws, size_t ws_size,
                              hipStream_t stream) {
  (void)in_sizes; (void)n_in; (void)out_size; (void)d_ws; (void)ws_size;
  const float* nbr    = (const float*)d_in[0];
  const float* ref    = (const float*)d_in[1];
  const float* w_off1 = (const float*)d_in[2];
  const float* b_off1 = (const float*)d_in[3];
  const float* w_off2 = (const float*)d_in[4];
  const float* b_off2 = (const float*)d_in[5];
  const float* w_co   = (const float*)d_in[6];
  const float* b_co   = (const float*)d_in[7];
  const float* w_dcn  = (const float*)d_in[8];
  const float* b_dcn  = (const float*)d_in[9];
  const float* w_coff1= (const float*)d_in[10];
  const float* b_coff1= (const float*)d_in[11];
  const float* w_coff2= (const float*)d_in[12];
  const float* b_coff2= (const float*)d_in[13];
  const float* w_cco  = (const float*)d_in[14];
  const float* b_cco  = (const float*)d_in[15];
  const float* w_cdcn = (const float*)d_in[16];
  const float* b_cdcn = (const float*)d_in[17];

  prep_wfrag<<<288, 256, 0, stream>>>(w_off1, 0, 64, 128, 1, 4);
  prep_wfrag<<<144, 256, 0, stream>>>(w_off2, 73728, 64, 64, 1, 4);
  prep_wfrag<<<504, 256, 0, stream>>>(w_co, 110592, 216, 64, 2, 7);
  prep_wfrag<<<288, 256, 0, stream>>>(w_coff1, 239616, 64, 128, 1, 4);
  prep_wfrag<<<144, 256, 0, stream>>>(w_coff2, 313344, 64, 64, 1, 4);
  prep_wfrag<<<504, 256, 0, stream>>>(w_cco, 350208, 216, 64, 2, 7);
  prep_wdcnfrag<<<144, 256, 0, stream>>>(w_dcn, 0);
  prep_wdcnfrag<<<144, 256, 0, stream>>>(w_cdcn, 36864);

  dim3 blk(256);
  float* out = (float*)d_out;
  // X1 = NHWC bf16(nbr)
  nchw2nhwc_bf<<<dim3(400, 4), blk, 0, stream>>>(nbr, 5);
  // A1 = lrelu(conv(cat(nbr,ref))); A2 = lrelu(conv(A1)); CO = conv(A2)
  conv_mfma<4><<<dim3(200, 1, 4), blk, 0, stream>>>(nbr, 0, 64, ref, 0, 64, 0, 4, b_off1, nullptr, 1, 64, 1);
  conv_mfma<4><<<dim3(200, 1, 4), blk, 0, stream>>>(nullptr, 1, 64, nullptr, 0, 0, 73728, 2, b_off2, nullptr, 2, 64, 1);
  conv_mfma<7><<<dim3(200, 2, 4), blk, 0, stream>>>(nullptr, 2, 64, nullptr, 0, 0, 110592, 2, b_co, nullptr, 4, 216, 2);
  // F1 = lrelu(dcn(X1, CO)) -> also X2 (NHWC bf16)
  dcn_k<<<dim3(800, 4), blk, 0, stream>>>(5, 0, b_dcn, nullptr, 3, 6);
  // cascade
  conv_mfma<4><<<dim3(200, 1, 4), blk, 0, stream>>>(nullptr, 3, 64, ref, 0, 64, 239616, 4, b_coff1, nullptr, 1, 64, 1);
  conv_mfma<4><<<dim3(200, 1, 4), blk, 0, stream>>>(nullptr, 1, 64, nullptr, 0, 0, 313344, 2, b_coff2, nullptr, 2, 64, 1);
  conv_mfma<7><<<dim3(200, 2, 4), blk, 0, stream>>>(nullptr, 2, 64, nullptr, 0, 0, 350208, 2, b_cco, nullptr, 4, 216, 2);
  // out = lrelu(dcn(X2, CO))
  dcn_k<<<dim3(800, 4), blk, 0, stream>>>(6, 36864, b_cdcn, out, 0, 0);
}